// Round 1
// baseline (862.476 us; speedup 1.0000x reference)
//
#include <hip/hip_runtime.h>

#define N_NODES 100000
#define N_EDGES 1600000
#define NEG_SLOPE 0.2f
#define BN_EPS 1e-5f

// ---------------- workspace layout (bytes) ----------------
static const size_t OFF_H    = 0;           // h   [N,256] f32 = 102,400,000
static const size_t OFF_RES  = 102400000;   // res+bias [N,256] f32
static const size_t OFF_EL   = 204800000;   // el  [N,4] f32
static const size_t OFF_ER   = 206400000;   // er  [N,4] f32
static const size_t OFF_DEG  = 208000000;   // deg [N] i32
static const size_t OFF_RS   = 208400000;   // row_start [N+1] i32
static const size_t OFF_CUR  = 208800016;   // cursor [N] i32
static const size_t OFF_ESRC = 209200016;   // edge src ids (CSR payload) [E] i32
static const size_t OFF_BS   = 215600016;   // block sums [128] i32
static const size_t OFF_BN   = 215600528;   // bn accum [128] f32 (sum, sumsq)
static const size_t OFF_SS   = 215601040;   // bn scale/shift [128] f32
// total ~215.6 MB

// ---------------- projection GEMM: [N,128] @ [128,512]^T -> h | res+bias ----
// block = 256 thr, tile = 32 rows x 128 cols, grid = (3125, 4)
__global__ __launch_bounds__(256, 2) void k_proj(
    const float* __restrict__ feats, const float* __restrict__ fc_w,
    const float* __restrict__ res_w, const float* __restrict__ bias,
    float* __restrict__ hbuf, float* __restrict__ resbuf)
{
  __shared__ float sB[128][132];            // W tile [col][k], +4 pad
  const int tid = threadIdx.x;
  const int rowBase = blockIdx.x * 32;
  const int gy = blockIdx.y;                // 0..3 -> cols gy*128..+127 of 512
  const float* W = (gy < 2) ? (fc_w + (size_t)gy * 128 * 128)
                            : (res_w + (size_t)(gy - 2) * 128 * 128);
  #pragma unroll
  for (int i = 0; i < 16; i++) {            // 128 cols x 32 k-chunks of float4
    int e = tid + i * 256;
    int c = e >> 5, kc = e & 31;
    float4 v = *(const float4*)(W + c * 128 + kc * 4);
    *(float4*)&sB[c][kc * 4] = v;           // banks: 33c+kc -> conflict-free
  }
  __syncthreads();
  const int cg = tid & 31, rg = tid >> 5;   // thread: rows 4rg..+3, cols 4cg..+3
  float acc[4][4] = {};
  const float* fp0 = feats + (size_t)(rowBase + rg * 4) * 128;
  #pragma unroll 4
  for (int k4 = 0; k4 < 32; k4++) {
    float4 b[4];
    #pragma unroll
    for (int j = 0; j < 4; j++) b[j] = *(const float4*)&sB[cg * 4 + j][k4 * 4];
    #pragma unroll
    for (int i = 0; i < 4; i++) {
      float4 a = *(const float4*)(fp0 + i * 128 + k4 * 4);  // 2 addrs/wave: HW broadcast
      #pragma unroll
      for (int j = 0; j < 4; j++) {
        acc[i][j] = fmaf(a.x, b[j].x, acc[i][j]);
        acc[i][j] = fmaf(a.y, b[j].y, acc[i][j]);
        acc[i][j] = fmaf(a.z, b[j].z, acc[i][j]);
        acc[i][j] = fmaf(a.w, b[j].w, acc[i][j]);
      }
    }
  }
  const int colLocal = cg * 4;
  if (gy < 2) {
    const int gcol = gy * 128 + colLocal;
    #pragma unroll
    for (int i = 0; i < 4; i++) {
      int grow = rowBase + rg * 4 + i;
      float4 v = make_float4(acc[i][0], acc[i][1], acc[i][2], acc[i][3]);
      *(float4*)(hbuf + (size_t)grow * 256 + gcol) = v;
    }
  } else {
    const int rcol = (gy - 2) * 128 + colLocal;
    const float4 bv = *(const float4*)(bias + rcol);
    #pragma unroll
    for (int i = 0; i < 4; i++) {
      int grow = rowBase + rg * 4 + i;
      float4 v = make_float4(acc[i][0] + bv.x, acc[i][1] + bv.y,
                             acc[i][2] + bv.z, acc[i][3] + bv.w);
      *(float4*)(resbuf + (size_t)grow * 256 + rcol) = v;
    }
  }
}

// ---------------- el/er: per-node attention logits ----------------
__global__ __launch_bounds__(256) void k_attn(
    const float* __restrict__ hbuf, const float* __restrict__ attn_l,
    const float* __restrict__ attn_r, float* __restrict__ el, float* __restrict__ er)
{
  const int gw = (blockIdx.x * 256 + threadIdx.x) >> 6;  // node = wave id
  const int lane = threadIdx.x & 63;
  if (gw >= N_NODES) return;
  const float4 hv = *(const float4*)(hbuf + (size_t)gw * 256 + lane * 4);
  const float4 al = *(const float4*)(attn_l + lane * 4);
  const float4 ar = *(const float4*)(attn_r + lane * 4);
  float pl = hv.x * al.x + hv.y * al.y + hv.z * al.z + hv.w * al.w;
  float pr = hv.x * ar.x + hv.y * ar.y + hv.z * ar.z + hv.w * ar.w;
  #pragma unroll
  for (int o = 1; o < 16; o <<= 1) {
    pl += __shfl_xor(pl, o, 64);
    pr += __shfl_xor(pr, o, 64);
  }
  if ((lane & 15) == 0) {
    int head = lane >> 4;
    el[gw * 4 + head] = pl;
    er[gw * 4 + head] = pr;
  }
}

// ---------------- CSR build ----------------
__global__ __launch_bounds__(256) void k_count(const int* __restrict__ dst, int* __restrict__ deg)
{
  int e = blockIdx.x * 256 + threadIdx.x;
  if (e < N_EDGES) atomicAdd(&deg[dst[e]], 1);
}

__global__ __launch_bounds__(256) void k_scan1(const int* __restrict__ deg,
                                               int* __restrict__ rs, int* __restrict__ bsums)
{
  __shared__ int tmp[256];
  const int t = threadIdx.x;
  const int base = blockIdx.x * 1024 + t * 4;
  int v0 = 0, v1 = 0, v2 = 0, v3 = 0;
  if (base + 0 < N_NODES) v0 = deg[base + 0];
  if (base + 1 < N_NODES) v1 = deg[base + 1];
  if (base + 2 < N_NODES) v2 = deg[base + 2];
  if (base + 3 < N_NODES) v3 = deg[base + 3];
  const int tsum = v0 + v1 + v2 + v3;
  tmp[t] = tsum;
  __syncthreads();
  for (int o = 1; o < 256; o <<= 1) {
    int x = (t >= o) ? tmp[t - o] : 0;
    __syncthreads();
    tmp[t] += x;
    __syncthreads();
  }
  const int excl = tmp[t] - tsum;
  if (base + 0 < N_NODES) rs[base + 0] = excl;
  if (base + 1 < N_NODES) rs[base + 1] = excl + v0;
  if (base + 2 < N_NODES) rs[base + 2] = excl + v0 + v1;
  if (base + 3 < N_NODES) rs[base + 3] = excl + v0 + v1 + v2;
  if (t == 255) bsums[blockIdx.x] = tmp[t];
}

__global__ void k_scan2(int* __restrict__ bsums)   // 1 block x 128 thr, nb=98
{
  __shared__ int tmp[128];
  const int t = threadIdx.x;
  const int v = (t < 98) ? bsums[t] : 0;
  tmp[t] = v;
  __syncthreads();
  for (int o = 1; o < 128; o <<= 1) {
    int x = (t >= o) ? tmp[t - o] : 0;
    __syncthreads();
    tmp[t] += x;
    __syncthreads();
  }
  if (t < 98) bsums[t] = tmp[t] - v;  // exclusive
}

__global__ __launch_bounds__(256) void k_scan3(int* __restrict__ rs,
                                               const int* __restrict__ bsums,
                                               int* __restrict__ cursor)
{
  int i = blockIdx.x * 256 + threadIdx.x;
  if (i < N_NODES) {
    int v = rs[i] + bsums[i >> 10];
    rs[i] = v;
    cursor[i] = v;
  } else if (i == N_NODES) {
    rs[N_NODES] = N_EDGES;
  }
}

__global__ __launch_bounds__(256) void k_scatter(const int* __restrict__ src,
                                                 const int* __restrict__ dst,
                                                 int* __restrict__ cursor,
                                                 int* __restrict__ esrc)
{
  int e = blockIdx.x * 256 + threadIdx.x;
  if (e >= N_EDGES) return;
  int d = dst[e];
  int pos = atomicAdd(&cursor[d], 1);
  esrc[pos] = src[e];   // store SRC node id directly: no edge-id indirection later
}

// ---------------- fused softmax + aggregation + residual/ELU/head-mean ------
// one wave per dst node (grid-stride); lane L: head L/16, dims 4*(L%16)..+3
__global__ __launch_bounds__(256) void k_agg(
    const float* __restrict__ hbuf, const float* __restrict__ resbuf,
    const float* __restrict__ el, const float* __restrict__ er,
    const int* __restrict__ rs, const int* __restrict__ esrc,
    float* __restrict__ out, float* __restrict__ bn)
{
  const int lane = threadIdx.x & 63;
  const int head = lane >> 4;
  const int waveG = blockIdx.x * 4 + (threadIdx.x >> 6);
  const int nW = gridDim.x * 4;
  float4 s4 = make_float4(0.f, 0.f, 0.f, 0.f);
  float4 q4 = make_float4(0.f, 0.f, 0.f, 0.f);
  for (int n = waveG; n < N_NODES; n += nW) {
    const int nu = __builtin_amdgcn_readfirstlane(n);
    const int p0 = rs[nu], p1 = rs[nu + 1];
    const float ern = er[nu * 4 + head];
    float4 acc = make_float4(0.f, 0.f, 0.f, 0.f);
    float ssum = 0.f;
    int sn_next = (p0 < p1) ? esrc[p0] : 0;
    for (int p = p0; p < p1; p++) {
      const int sn = sn_next;
      if (p + 1 < p1) sn_next = esrc[p + 1];        // prefetch next src id
      float e = el[sn * 4 + head] + ern;
      e = (e > 0.f) ? e : NEG_SLOPE * e;
      const float w = __expf(e);                     // |e| small: max-free softmax
      ssum += w;
      const float4 hv = *(const float4*)(hbuf + (size_t)sn * 256 + lane * 4);
      acc.x = fmaf(w, hv.x, acc.x);
      acc.y = fmaf(w, hv.y, acc.y);
      acc.z = fmaf(w, hv.z, acc.z);
      acc.w = fmaf(w, hv.w, acc.w);
    }
    const float inv = (p1 > p0) ? (1.0f / ssum) : 0.f;   // deg-0 guard
    const float4 rv = *(const float4*)(resbuf + (size_t)nu * 256 + lane * 4);
    float4 v;
    v.x = fmaf(acc.x, inv, rv.x);
    v.y = fmaf(acc.y, inv, rv.y);
    v.z = fmaf(acc.z, inv, rv.z);
    v.w = fmaf(acc.w, inv, rv.w);
    v.x = (v.x > 0.f) ? v.x : (__expf(v.x) - 1.f);   // elu
    v.y = (v.y > 0.f) ? v.y : (__expf(v.y) - 1.f);
    v.z = (v.z > 0.f) ? v.z : (__expf(v.z) - 1.f);
    v.w = (v.w > 0.f) ? v.w : (__expf(v.w) - 1.f);
    v.x += __shfl_xor(v.x, 16, 64);  v.x += __shfl_xor(v.x, 32, 64);  // head mean
    v.y += __shfl_xor(v.y, 16, 64);  v.y += __shfl_xor(v.y, 32, 64);
    v.z += __shfl_xor(v.z, 16, 64);  v.z += __shfl_xor(v.z, 32, 64);
    v.w += __shfl_xor(v.w, 16, 64);  v.w += __shfl_xor(v.w, 32, 64);
    if (lane < 16) {
      v.x *= 0.25f; v.y *= 0.25f; v.z *= 0.25f; v.w *= 0.25f;
      *(float4*)(out + (size_t)nu * 64 + lane * 4) = v;
      s4.x += v.x; s4.y += v.y; s4.z += v.z; s4.w += v.w;
      q4.x += v.x * v.x; q4.y += v.y * v.y; q4.z += v.z * v.z; q4.w += v.w * v.w;
    }
  }
  __shared__ float lsum[64], lsq[64];
  if (threadIdx.x < 64) { lsum[threadIdx.x] = 0.f; lsq[threadIdx.x] = 0.f; }
  __syncthreads();
  if (lane < 16) {
    atomicAdd(&lsum[lane * 4 + 0], s4.x);  atomicAdd(&lsq[lane * 4 + 0], q4.x);
    atomicAdd(&lsum[lane * 4 + 1], s4.y);  atomicAdd(&lsq[lane * 4 + 1], q4.y);
    atomicAdd(&lsum[lane * 4 + 2], s4.z);  atomicAdd(&lsq[lane * 4 + 2], q4.z);
    atomicAdd(&lsum[lane * 4 + 3], s4.w);  atomicAdd(&lsq[lane * 4 + 3], q4.w);
  }
  __syncthreads();
  if (threadIdx.x < 64) {
    atomicAdd(&bn[threadIdx.x], lsum[threadIdx.x]);
    atomicAdd(&bn[64 + threadIdx.x], lsq[threadIdx.x]);
  }
}

// ---------------- batchnorm ----------------
__global__ void k_bn_stats(const float* __restrict__ bn, const float* __restrict__ gamma,
                           const float* __restrict__ beta, float* __restrict__ ss)
{
  int d = threadIdx.x;  // 64 threads
  float mean = bn[d] * (1.0f / N_NODES);
  float var = bn[64 + d] * (1.0f / N_NODES) - mean * mean;
  float sc = gamma[d] * rsqrtf(var + BN_EPS);
  ss[d] = sc;
  ss[64 + d] = beta[d] - mean * sc;
}

__global__ __launch_bounds__(256) void k_bn_apply(float* __restrict__ out,
                                                  const float* __restrict__ ss)
{
  int i = blockIdx.x * 256 + threadIdx.x;   // float4 index, N*16 total
  if (i >= N_NODES * 16) return;
  int d0 = (i & 15) * 4;
  float4 v = *(float4*)(out + (size_t)i * 4);
  float4 sc = *(const float4*)(ss + d0);
  float4 sh = *(const float4*)(ss + 64 + d0);
  v.x = fmaf(v.x, sc.x, sh.x);
  v.y = fmaf(v.y, sc.y, sh.y);
  v.z = fmaf(v.z, sc.z, sh.z);
  v.w = fmaf(v.w, sc.w, sh.w);
  *(float4*)(out + (size_t)i * 4) = v;
}

extern "C" void kernel_launch(void* const* d_in, const int* in_sizes, int n_in,
                              void* d_out, int out_size, void* d_ws, size_t ws_size,
                              hipStream_t stream)
{
  const float* feats  = (const float*)d_in[0];
  const int*   src    = (const int*)d_in[1];
  const int*   dst    = (const int*)d_in[2];
  const float* fc_w   = (const float*)d_in[3];
  const float* attn_l = (const float*)d_in[4];
  const float* attn_r = (const float*)d_in[5];
  const float* res_w  = (const float*)d_in[6];
  const float* bias   = (const float*)d_in[7];
  const float* gamma  = (const float*)d_in[8];
  const float* beta   = (const float*)d_in[9];

  char* ws = (char*)d_ws;
  float* hbuf   = (float*)(ws + OFF_H);
  float* resbuf = (float*)(ws + OFF_RES);
  float* elb    = (float*)(ws + OFF_EL);
  float* erb    = (float*)(ws + OFF_ER);
  int*   deg    = (int*)(ws + OFF_DEG);
  int*   rsb    = (int*)(ws + OFF_RS);
  int*   curb   = (int*)(ws + OFF_CUR);
  int*   esrc   = (int*)(ws + OFF_ESRC);
  int*   bsums  = (int*)(ws + OFF_BS);
  float* bnb    = (float*)(ws + OFF_BN);
  float* ssb    = (float*)(ws + OFF_SS);
  float* outp   = (float*)d_out;

  hipMemsetAsync(deg, 0, N_NODES * sizeof(int), stream);
  hipMemsetAsync(bnb, 0, 128 * sizeof(float), stream);

  k_proj<<<dim3(3125, 4), 256, 0, stream>>>(feats, fc_w, res_w, bias, hbuf, resbuf);
  k_attn<<<25000, 256, 0, stream>>>(hbuf, attn_l, attn_r, elb, erb);
  k_count<<<6250, 256, 0, stream>>>(dst, deg);
  k_scan1<<<98, 256, 0, stream>>>(deg, rsb, bsums);
  k_scan2<<<1, 128, 0, stream>>>(bsums);
  k_scan3<<<391, 256, 0, stream>>>(rsb, bsums, curb);
  k_scatter<<<6250, 256, 0, stream>>>(src, dst, curb, esrc);
  k_agg<<<2048, 256, 0, stream>>>(hbuf, resbuf, elb, erb, rsb, esrc, outp, bnb);
  k_bn_stats<<<1, 64, 0, stream>>>(bnb, gamma, beta, ssb);
  k_bn_apply<<<6250, 256, 0, stream>>>(outp, ssb);
}

// Round 2
// 573.500 us; speedup vs baseline: 1.5039x; 1.5039x over previous
//
#include <hip/hip_runtime.h>

#define N_NODES 100000
#define N_PAD   100096      // 782 * 128
#define N_EDGES 1600000
#define NEG_SLOPE 0.2f
#define BN_EPS 1e-5f

typedef __attribute__((ext_vector_type(8))) short short8;
typedef __attribute__((ext_vector_type(4))) float floatx4;

// ---------------- workspace layout (bytes) ----------------
static const size_t OFF_AB   = 0;            // feats bf16 fragment-ordered [N_PAD,128] = 25,624,576
static const size_t OFF_BB   = 25624576;     // weights bf16 fragment-ordered [512,128] = 131,072
static const size_t OFF_H    = 25755648;     // h bf16 [N,256] = 51,200,000
static const size_t OFF_RES  = 76955648;     // res+bias bf16 [N,256] = 51,200,000
static const size_t OFF_EL   = 128155648;    // el [N,4] f32
static const size_t OFF_ER   = 129755648;    // er [N,4] f32
static const size_t OFF_DEG  = 131355648;    // deg [N] i32
static const size_t OFF_RS   = 131755648;    // row_start [N+1] i32
static const size_t OFF_CUR  = 132155664;    // cursor [N] i32
static const size_t OFF_ESRC = 132555664;    // edge src ids [E] i32
static const size_t OFF_BS   = 138955664;    // block sums [128] i32
static const size_t OFF_BN   = 138956176;    // bn accum [128] f32
static const size_t OFF_SS   = 138956688;    // bn scale/shift [128] f32
// total ~139 MB (previous round used 215.6 MB successfully)

__device__ __forceinline__ unsigned short f2bf(float x) {
  unsigned int u = __float_as_uint(x);
  unsigned int r = (u + 0x7fffu + ((u >> 16) & 1u)) >> 16;   // RNE
  return (unsigned short)r;
}
__device__ __forceinline__ float bf2f(unsigned short u) {
  return __uint_as_float(((unsigned int)u) << 16);
}

// ---------------- converters: fp32 -> bf16, fragment-ordered ----------------
// fragment-order chunk index for (row r, k-chunk j in 0..15):
//   blk=r>>7, t=(r>>4)&7, s=j>>2, q=j&3  ->  blk*2048 + t*256 + s*64 + (r&15) + 16*q
__global__ __launch_bounds__(256) void k_cvt_a(const float* __restrict__ feats,
                                               unsigned short* __restrict__ Ab)
{
  int c = blockIdx.x * 256 + threadIdx.x;   // chunk id, N_PAD*16 total
  int r = c >> 4, j = c & 15;
  unsigned short v[8];
  if (r < N_NODES) {
    const float* p = feats + (size_t)r * 128 + j * 8;
    float4 a = *(const float4*)p, b = *(const float4*)(p + 4);
    v[0]=f2bf(a.x); v[1]=f2bf(a.y); v[2]=f2bf(a.z); v[3]=f2bf(a.w);
    v[4]=f2bf(b.x); v[5]=f2bf(b.y); v[6]=f2bf(b.z); v[7]=f2bf(b.w);
  } else {
    for (int i = 0; i < 8; i++) v[i] = 0;
  }
  size_t idx = (size_t)(r >> 7) * 2048 + ((r >> 4) & 7) * 256 + (j >> 2) * 64
             + (r & 15) + 16 * (j & 3);
  *(short8*)(Ab + idx * 8) = *(short8*)v;
}

__global__ __launch_bounds__(256) void k_cvt_w(const float* __restrict__ fc_w,
                                               const float* __restrict__ res_w,
                                               unsigned short* __restrict__ Bb)
{
  int c = blockIdx.x * 256 + threadIdx.x;   // 512*16 = 8192 chunks
  int n = c >> 4, j = c & 15;
  const float* W = (n < 256) ? (fc_w + (size_t)n * 128) : (res_w + (size_t)(n - 256) * 128);
  const float* p = W + j * 8;
  float4 a = *(const float4*)p, b = *(const float4*)(p + 4);
  unsigned short v[8];
  v[0]=f2bf(a.x); v[1]=f2bf(a.y); v[2]=f2bf(a.z); v[3]=f2bf(a.w);
  v[4]=f2bf(b.x); v[5]=f2bf(b.y); v[6]=f2bf(b.z); v[7]=f2bf(b.w);
  size_t idx = (size_t)(n >> 7) * 2048 + ((n >> 4) & 7) * 256 + (j >> 2) * 64
             + (n & 15) + 16 * (j & 3);
  *(short8*)(Bb + idx * 8) = *(short8*)v;
}

// ---------------- MFMA projection: [N,128]bf16 @ [128,512] -> h|res (bf16) --
// block 256 thr = 4 waves, tile 128 rows x 128 cols, K=128. grid (782, 4).
// wave w: mhalf=w&1 (64 rows), nhalf=w>>1 (64 cols); 4x4 grid of 16x16 tiles.
__global__ __launch_bounds__(256, 3) void k_mm(
    const unsigned short* __restrict__ Ab, const unsigned short* __restrict__ Bb,
    const float* __restrict__ bias,
    unsigned short* __restrict__ hbuf, unsigned short* __restrict__ resbuf)
{
  __shared__ unsigned short sA[16384];  // 32 KB, fragment-ordered copy of A block
  const int tid = threadIdx.x;
  const int w = tid >> 6, L = tid & 63;
  const int blk = blockIdx.x, nb = blockIdx.y;

  {  // stage A: contiguous 32 KB, global_load_lds width 16
    const unsigned short* ga = Ab + (size_t)blk * 16384;
    #pragma unroll
    for (int i = 0; i < 8; i++) {
      int off = (i * 256 + w * 64) * 8;   // ushort offset, wave-uniform base
      __builtin_amdgcn_global_load_lds(
          (const __attribute__((address_space(1))) unsigned int*)(ga + off + L * 8),
          (__attribute__((address_space(3))) unsigned int*)(sA + off),
          16, 0, 0);
    }
  }
  const int mh = w & 1, nh = w >> 1;
  floatx4 acc[4][4] = {};
  __syncthreads();   // drains vmcnt for the staging loads

  const unsigned short* gb = Bb + ((size_t)nb * 2048 + nh * 4 * 256) * 8 + L * 8;
  #pragma unroll
  for (int s = 0; s < 4; s++) {          // k-steps of 32
    short8 a[4], b[4];
    #pragma unroll
    for (int t = 0; t < 4; t++)
      a[t] = *(const short8*)(sA + ((mh * 4 + t) * 256 + s * 64 + L) * 8);  // stride-1 b128
    #pragma unroll
    for (int t = 0; t < 4; t++)
      b[t] = *(const short8*)(gb + ((size_t)t * 256 + s * 64) * 8);          // L2-hot
    #pragma unroll
    for (int mt = 0; mt < 4; mt++)
      #pragma unroll
      for (int nt = 0; nt < 4; nt++)
        acc[mt][nt] = __builtin_amdgcn_mfma_f32_16x16x32_bf16(a[mt], b[nt], acc[mt][nt], 0, 0, 0);
  }

  // epilogue: C row = r0 + mt*16 + (L>>4)*4 + reg, col = col0 + nt*16 + (L&15)
  const int q = L >> 4, cn = L & 15;
  const int r0 = blk * 128 + mh * 64;
  if (nb < 2) {
    const int col0 = nb * 128 + nh * 64;
    #pragma unroll
    for (int mt = 0; mt < 4; mt++)
      #pragma unroll
      for (int r = 0; r < 4; r++) {
        int row = r0 + mt * 16 + q * 4 + r;
        if (row < N_NODES)
          #pragma unroll
          for (int nt = 0; nt < 4; nt++)
            hbuf[(size_t)row * 256 + col0 + nt * 16 + cn] = f2bf(acc[mt][nt][r]);
      }
  } else {
    const int rc0 = (nb - 2) * 128 + nh * 64;
    #pragma unroll
    for (int mt = 0; mt < 4; mt++)
      #pragma unroll
      for (int r = 0; r < 4; r++) {
        int row = r0 + mt * 16 + q * 4 + r;
        if (row < N_NODES)
          #pragma unroll
          for (int nt = 0; nt < 4; nt++) {
            float v = acc[mt][nt][r] + bias[rc0 + nt * 16 + cn];
            resbuf[(size_t)row * 256 + rc0 + nt * 16 + cn] = f2bf(v);
          }
      }
  }
}

// ---------------- el/er: per-node attention logits (bf16 h) ----------------
__global__ __launch_bounds__(256) void k_attn(
    const unsigned short* __restrict__ hbuf, const float* __restrict__ attn_l,
    const float* __restrict__ attn_r, float* __restrict__ el, float* __restrict__ er)
{
  const int gw = (blockIdx.x * 256 + threadIdx.x) >> 6;
  const int lane = threadIdx.x & 63;
  if (gw >= N_NODES) return;
  const ushort4 hv4 = *(const ushort4*)(hbuf + (size_t)gw * 256 + lane * 4);
  const float4 al = *(const float4*)(attn_l + lane * 4);
  const float4 ar = *(const float4*)(attn_r + lane * 4);
  float hx = bf2f(hv4.x), hy = bf2f(hv4.y), hz = bf2f(hv4.z), hw = bf2f(hv4.w);
  float pl = hx * al.x + hy * al.y + hz * al.z + hw * al.w;
  float pr = hx * ar.x + hy * ar.y + hz * ar.z + hw * ar.w;
  #pragma unroll
  for (int o = 1; o < 16; o <<= 1) {
    pl += __shfl_xor(pl, o, 64);
    pr += __shfl_xor(pr, o, 64);
  }
  if ((lane & 15) == 0) {
    int head = lane >> 4;
    el[gw * 4 + head] = pl;
    er[gw * 4 + head] = pr;
  }
}

// ---------------- CSR build ----------------
__global__ __launch_bounds__(256) void k_count(const int* __restrict__ dst, int* __restrict__ deg)
{
  int e = blockIdx.x * 256 + threadIdx.x;
  if (e < N_EDGES) atomicAdd(&deg[dst[e]], 1);
}

__global__ __launch_bounds__(256) void k_scan1(const int* __restrict__ deg,
                                               int* __restrict__ rs, int* __restrict__ bsums)
{
  __shared__ int tmp[256];
  const int t = threadIdx.x;
  const int base = blockIdx.x * 1024 + t * 4;
  int v0 = 0, v1 = 0, v2 = 0, v3 = 0;
  if (base + 0 < N_NODES) v0 = deg[base + 0];
  if (base + 1 < N_NODES) v1 = deg[base + 1];
  if (base + 2 < N_NODES) v2 = deg[base + 2];
  if (base + 3 < N_NODES) v3 = deg[base + 3];
  const int tsum = v0 + v1 + v2 + v3;
  tmp[t] = tsum;
  __syncthreads();
  for (int o = 1; o < 256; o <<= 1) {
    int x = (t >= o) ? tmp[t - o] : 0;
    __syncthreads();
    tmp[t] += x;
    __syncthreads();
  }
  const int excl = tmp[t] - tsum;
  if (base + 0 < N_NODES) rs[base + 0] = excl;
  if (base + 1 < N_NODES) rs[base + 1] = excl + v0;
  if (base + 2 < N_NODES) rs[base + 2] = excl + v0 + v1;
  if (base + 3 < N_NODES) rs[base + 3] = excl + v0 + v1 + v2;
  if (t == 255) bsums[blockIdx.x] = tmp[t];
}

__global__ void k_scan2(int* __restrict__ bsums)
{
  __shared__ int tmp[128];
  const int t = threadIdx.x;
  const int v = (t < 98) ? bsums[t] : 0;
  tmp[t] = v;
  __syncthreads();
  for (int o = 1; o < 128; o <<= 1) {
    int x = (t >= o) ? tmp[t - o] : 0;
    __syncthreads();
    tmp[t] += x;
    __syncthreads();
  }
  if (t < 98) bsums[t] = tmp[t] - v;
}

__global__ __launch_bounds__(256) void k_scan3(int* __restrict__ rs,
                                               const int* __restrict__ bsums,
                                               int* __restrict__ cursor)
{
  int i = blockIdx.x * 256 + threadIdx.x;
  if (i < N_NODES) {
    int v = rs[i] + bsums[i >> 10];
    rs[i] = v;
    cursor[i] = v;
  } else if (i == N_NODES) {
    rs[N_NODES] = N_EDGES;
  }
}

__global__ __launch_bounds__(256) void k_scatter(const int* __restrict__ src,
                                                 const int* __restrict__ dst,
                                                 int* __restrict__ cursor,
                                                 int* __restrict__ esrc)
{
  int e = blockIdx.x * 256 + threadIdx.x;
  if (e >= N_EDGES) return;
  int d = dst[e];
  int pos = atomicAdd(&cursor[d], 1);
  esrc[pos] = src[e];
}

// ---------------- fused softmax + aggregation + residual/ELU/head-mean ------
__global__ __launch_bounds__(256) void k_agg(
    const unsigned short* __restrict__ hbuf, const unsigned short* __restrict__ resbuf,
    const float* __restrict__ el, const float* __restrict__ er,
    const int* __restrict__ rs, const int* __restrict__ esrc,
    float* __restrict__ out, float* __restrict__ bn)
{
  const int lane = threadIdx.x & 63;
  const int head = lane >> 4;
  const int waveG = blockIdx.x * 4 + (threadIdx.x >> 6);
  const int nW = gridDim.x * 4;
  float4 s4 = make_float4(0.f, 0.f, 0.f, 0.f);
  float4 q4 = make_float4(0.f, 0.f, 0.f, 0.f);
  for (int n = waveG; n < N_NODES; n += nW) {
    const int nu = __builtin_amdgcn_readfirstlane(n);
    const int p0 = rs[nu], p1 = rs[nu + 1];
    const float ern = er[nu * 4 + head];
    float4 acc = make_float4(0.f, 0.f, 0.f, 0.f);
    float ssum = 0.f;
    int sn_next = (p0 < p1) ? esrc[p0] : 0;
    for (int p = p0; p < p1; p++) {
      const int sn = sn_next;
      if (p + 1 < p1) sn_next = esrc[p + 1];
      float e = el[sn * 4 + head] + ern;
      e = (e > 0.f) ? e : NEG_SLOPE * e;
      const float wgt = __expf(e);
      ssum += wgt;
      const ushort4 hv4 = *(const ushort4*)(hbuf + (size_t)sn * 256 + lane * 4);
      acc.x = fmaf(wgt, bf2f(hv4.x), acc.x);
      acc.y = fmaf(wgt, bf2f(hv4.y), acc.y);
      acc.z = fmaf(wgt, bf2f(hv4.z), acc.z);
      acc.w = fmaf(wgt, bf2f(hv4.w), acc.w);
    }
    const float inv = (p1 > p0) ? (1.0f / ssum) : 0.f;
    const ushort4 rv4 = *(const ushort4*)(resbuf + (size_t)nu * 256 + lane * 4);
    float4 v;
    v.x = fmaf(acc.x, inv, bf2f(rv4.x));
    v.y = fmaf(acc.y, inv, bf2f(rv4.y));
    v.z = fmaf(acc.z, inv, bf2f(rv4.z));
    v.w = fmaf(acc.w, inv, bf2f(rv4.w));
    v.x = (v.x > 0.f) ? v.x : (__expf(v.x) - 1.f);
    v.y = (v.y > 0.f) ? v.y : (__expf(v.y) - 1.f);
    v.z = (v.z > 0.f) ? v.z : (__expf(v.z) - 1.f);
    v.w = (v.w > 0.f) ? v.w : (__expf(v.w) - 1.f);
    v.x += __shfl_xor(v.x, 16, 64);  v.x += __shfl_xor(v.x, 32, 64);
    v.y += __shfl_xor(v.y, 16, 64);  v.y += __shfl_xor(v.y, 32, 64);
    v.z += __shfl_xor(v.z, 16, 64);  v.z += __shfl_xor(v.z, 32, 64);
    v.w += __shfl_xor(v.w, 16, 64);  v.w += __shfl_xor(v.w, 32, 64);
    if (lane < 16) {
      v.x *= 0.25f; v.y *= 0.25f; v.z *= 0.25f; v.w *= 0.25f;
      *(float4*)(out + (size_t)nu * 64 + lane * 4) = v;
      s4.x += v.x; s4.y += v.y; s4.z += v.z; s4.w += v.w;
      q4.x += v.x * v.x; q4.y += v.y * v.y; q4.z += v.z * v.z; q4.w += v.w * v.w;
    }
  }
  __shared__ float lsum[64], lsq[64];
  if (threadIdx.x < 64) { lsum[threadIdx.x] = 0.f; lsq[threadIdx.x] = 0.f; }
  __syncthreads();
  if (lane < 16) {
    atomicAdd(&lsum[lane * 4 + 0], s4.x);  atomicAdd(&lsq[lane * 4 + 0], q4.x);
    atomicAdd(&lsum[lane * 4 + 1], s4.y);  atomicAdd(&lsq[lane * 4 + 1], q4.y);
    atomicAdd(&lsum[lane * 4 + 2], s4.z);  atomicAdd(&lsq[lane * 4 + 2], q4.z);
    atomicAdd(&lsum[lane * 4 + 3], s4.w);  atomicAdd(&lsq[lane * 4 + 3], q4.w);
  }
  __syncthreads();
  if (threadIdx.x < 64) {
    atomicAdd(&bn[threadIdx.x], lsum[threadIdx.x]);
    atomicAdd(&bn[64 + threadIdx.x], lsq[threadIdx.x]);
  }
}

// ---------------- batchnorm ----------------
__global__ void k_bn_stats(const float* __restrict__ bn, const float* __restrict__ gamma,
                           const float* __restrict__ beta, float* __restrict__ ss)
{
  int d = threadIdx.x;
  float mean = bn[d] * (1.0f / N_NODES);
  float var = bn[64 + d] * (1.0f / N_NODES) - mean * mean;
  float sc = gamma[d] * rsqrtf(var + BN_EPS);
  ss[d] = sc;
  ss[64 + d] = beta[d] - mean * sc;
}

__global__ __launch_bounds__(256) void k_bn_apply(float* __restrict__ out,
                                                  const float* __restrict__ ss)
{
  int i = blockIdx.x * 256 + threadIdx.x;
  if (i >= N_NODES * 16) return;
  int d0 = (i & 15) * 4;
  float4 v = *(float4*)(out + (size_t)i * 4);
  float4 sc = *(const float4*)(ss + d0);
  float4 sh = *(const float4*)(ss + 64 + d0);
  v.x = fmaf(v.x, sc.x, sh.x);
  v.y = fmaf(v.y, sc.y, sh.y);
  v.z = fmaf(v.z, sc.z, sh.z);
  v.w = fmaf(v.w, sc.w, sh.w);
  *(float4*)(out + (size_t)i * 4) = v;
}

extern "C" void kernel_launch(void* const* d_in, const int* in_sizes, int n_in,
                              void* d_out, int out_size, void* d_ws, size_t ws_size,
                              hipStream_t stream)
{
  const float* feats  = (const float*)d_in[0];
  const int*   src    = (const int*)d_in[1];
  const int*   dst    = (const int*)d_in[2];
  const float* fc_w   = (const float*)d_in[3];
  const float* attn_l = (const float*)d_in[4];
  const float* attn_r = (const float*)d_in[5];
  const float* res_w  = (const float*)d_in[6];
  const float* bias   = (const float*)d_in[7];
  const float* gamma  = (const float*)d_in[8];
  const float* beta   = (const float*)d_in[9];

  char* ws = (char*)d_ws;
  unsigned short* Ab     = (unsigned short*)(ws + OFF_AB);
  unsigned short* Bb     = (unsigned short*)(ws + OFF_BB);
  unsigned short* hbuf   = (unsigned short*)(ws + OFF_H);
  unsigned short* resbuf = (unsigned short*)(ws + OFF_RES);
  float* elb    = (float*)(ws + OFF_EL);
  float* erb    = (float*)(ws + OFF_ER);
  int*   deg    = (int*)(ws + OFF_DEG);
  int*   rsb    = (int*)(ws + OFF_RS);
  int*   curb   = (int*)(ws + OFF_CUR);
  int*   esrc   = (int*)(ws + OFF_ESRC);
  int*   bsums  = (int*)(ws + OFF_BS);
  float* bnb    = (float*)(ws + OFF_BN);
  float* ssb    = (float*)(ws + OFF_SS);
  float* outp   = (float*)d_out;

  hipMemsetAsync(deg, 0, N_NODES * sizeof(int), stream);
  hipMemsetAsync(bnb, 0, 128 * sizeof(float), stream);

  k_cvt_w<<<32, 256, 0, stream>>>(fc_w, res_w, Bb);
  k_cvt_a<<<N_PAD * 16 / 256, 256, 0, stream>>>(feats, Ab);
  k_mm<<<dim3(782, 4), 256, 0, stream>>>(Ab, Bb, bias, hbuf, resbuf);
  k_attn<<<25000, 256, 0, stream>>>(hbuf, attn_l, attn_r, elb, erb);
  k_count<<<6250, 256, 0, stream>>>(dst, deg);
  k_scan1<<<98, 256, 0, stream>>>(deg, rsb, bsums);
  k_scan2<<<1, 128, 0, stream>>>(bsums);
  k_scan3<<<391, 256, 0, stream>>>(rsb, bsums, curb);
  k_scatter<<<6250, 256, 0, stream>>>(src, dst, curb, esrc);
  k_agg<<<2048, 256, 0, stream>>>(hbuf, resbuf, elb, erb, rsb, esrc, outp, bnb);
  k_bn_stats<<<1, 64, 0, stream>>>(bnb, gamma, beta, ssb);
  k_bn_apply<<<6250, 256, 0, stream>>>(outp, ssb);
}

// Round 3
// 532.120 us; speedup vs baseline: 1.6208x; 1.0778x over previous
//
#include <hip/hip_runtime.h>

#define N_NODES 100000
#define N_PAD   100096      // 782 * 128
#define N_EDGES 1600000
#define NEG_SLOPE 0.2f
#define BN_EPS 1e-5f

typedef __attribute__((ext_vector_type(8))) short short8;
typedef __attribute__((ext_vector_type(4))) float floatx4;

// ---------------- workspace layout (bytes) ----------------
static const size_t OFF_AB   = 0;            // feats bf16 fragment-ordered [N_PAD,128]
static const size_t OFF_BB   = 25624576;     // weights bf16 fragment-ordered [512,128]
static const size_t OFF_H    = 25755648;     // h bf16 [N,256]
static const size_t OFF_RES  = 76955648;     // res+bias bf16 [N,256]
static const size_t OFF_EL   = 128155648;    // el [N,4] f32
static const size_t OFF_ER   = 129755648;    // er [N,4] f32
static const size_t OFF_DEG  = 131355648;    // deg [N] i32
static const size_t OFF_RS   = 131755648;    // row_start [N+1] i32
static const size_t OFF_CUR  = 132155664;    // cursor [N] i32
static const size_t OFF_ESRC = 132555664;    // edge src ids [E] i32
static const size_t OFF_BS   = 138955664;    // block sums [128] i32
static const size_t OFF_BN   = 138956176;    // bn accum [128] f32
// total ~139 MB

__device__ __forceinline__ unsigned short f2bf(float x) {
  unsigned int u = __float_as_uint(x);
  unsigned int r = (u + 0x7fffu + ((u >> 16) & 1u)) >> 16;   // RNE
  return (unsigned short)r;
}
__device__ __forceinline__ float bf2f(unsigned short u) {
  return __uint_as_float(((unsigned int)u) << 16);
}

// ---------------- fused pre-pass: cvt_a | edge count | cvt_w ----------------
// fragment-order chunk index for (row r, k-chunk j in 0..15):
//   blk=r>>7, t=(r>>4)&7, s=j>>2, q=j&3  ->  blk*2048 + t*256 + s*64 + (r&15) + 16*q
__global__ __launch_bounds__(256) void k_pre(
    const float* __restrict__ feats, const float* __restrict__ fc_w,
    const float* __restrict__ res_w, const int* __restrict__ dst,
    unsigned short* __restrict__ Ab, unsigned short* __restrict__ Bb,
    int* __restrict__ deg)
{
  const int b = blockIdx.x;
  if (b < 6256) {                                // ---- cvt_a: N_PAD*16 chunks
    int c = b * 256 + threadIdx.x;
    int r = c >> 4, j = c & 15;
    unsigned short v[8];
    if (r < N_NODES) {
      const float* p = feats + (size_t)r * 128 + j * 8;
      float4 a = *(const float4*)p, bb = *(const float4*)(p + 4);
      v[0]=f2bf(a.x); v[1]=f2bf(a.y); v[2]=f2bf(a.z); v[3]=f2bf(a.w);
      v[4]=f2bf(bb.x); v[5]=f2bf(bb.y); v[6]=f2bf(bb.z); v[7]=f2bf(bb.w);
    } else {
      for (int i = 0; i < 8; i++) v[i] = 0;
    }
    size_t idx = (size_t)(r >> 7) * 2048 + ((r >> 4) & 7) * 256 + (j >> 2) * 64
               + (r & 15) + 16 * (j & 3);
    *(short8*)(Ab + idx * 8) = *(short8*)v;
  } else if (b < 12506) {                        // ---- count degrees
    int e = (b - 6256) * 256 + threadIdx.x;
    if (e < N_EDGES) atomicAdd(&deg[dst[e]], 1);
  } else {                                       // ---- cvt_w: 8192 chunks
    int c = (b - 12506) * 256 + threadIdx.x;
    int n = c >> 4, j = c & 15;
    const float* W = (n < 256) ? (fc_w + (size_t)n * 128) : (res_w + (size_t)(n - 256) * 128);
    const float* p = W + j * 8;
    float4 a = *(const float4*)p, bb = *(const float4*)(p + 4);
    unsigned short v[8];
    v[0]=f2bf(a.x); v[1]=f2bf(a.y); v[2]=f2bf(a.z); v[3]=f2bf(a.w);
    v[4]=f2bf(bb.x); v[5]=f2bf(bb.y); v[6]=f2bf(bb.z); v[7]=f2bf(bb.w);
    size_t idx = (size_t)(n >> 7) * 2048 + ((n >> 4) & 7) * 256 + (j >> 2) * 64
               + (n & 15) + 16 * (j & 3);
    *(short8*)(Bb + idx * 8) = *(short8*)v;
  }
}

// ---------------- MFMA projection + fused el/er -----------------------------
// block 256 thr = 4 waves, tile 128 rows x 128 cols, K=128. grid (782, 4).
// wave w: mh=w&1 (64 rows), nh=w>>1 (64 cols). nb<2 -> h (+el/er), nb>=2 -> res.
__global__ __launch_bounds__(256) void k_mm(
    const unsigned short* __restrict__ Ab, const unsigned short* __restrict__ Bb,
    const float* __restrict__ bias, const float* __restrict__ attn_l,
    const float* __restrict__ attn_r,
    unsigned short* __restrict__ hbuf, unsigned short* __restrict__ resbuf,
    float* __restrict__ el, float* __restrict__ er)
{
  __shared__ unsigned short sA[16384];  // 32 KB, fragment-ordered A block
  const int tid = threadIdx.x;
  const int w = tid >> 6, L = tid & 63;
  const int blk = blockIdx.x, nb = blockIdx.y;

  {  // stage A: contiguous 32 KB, global_load_lds width 16
    const unsigned short* ga = Ab + (size_t)blk * 16384;
    #pragma unroll
    for (int i = 0; i < 8; i++) {
      int off = (i * 256 + w * 64) * 8;
      __builtin_amdgcn_global_load_lds(
          (const __attribute__((address_space(1))) unsigned int*)(ga + off + L * 8),
          (__attribute__((address_space(3))) unsigned int*)(sA + off),
          16, 0, 0);
    }
  }
  const int mh = w & 1, nh = w >> 1;
  floatx4 acc[4][4] = {};
  __syncthreads();

  const unsigned short* gb = Bb + ((size_t)nb * 2048 + nh * 4 * 256) * 8 + L * 8;
  #pragma unroll
  for (int s = 0; s < 4; s++) {
    short8 a[4], b[4];
    #pragma unroll
    for (int t = 0; t < 4; t++)
      a[t] = *(const short8*)(sA + ((mh * 4 + t) * 256 + s * 64 + L) * 8);
    #pragma unroll
    for (int t = 0; t < 4; t++)
      b[t] = *(const short8*)(gb + ((size_t)t * 256 + s * 64) * 8);
    #pragma unroll
    for (int mt = 0; mt < 4; mt++)
      #pragma unroll
      for (int nt = 0; nt < 4; nt++)
        acc[mt][nt] = __builtin_amdgcn_mfma_f32_16x16x32_bf16(a[mt], b[nt], acc[mt][nt], 0, 0, 0);
  }

  // epilogue: row = r0 + mt*16 + q*4 + r, col = col0 + nt*16 + cn
  const int q = L >> 4, cn = L & 15;
  const int r0 = blk * 128 + mh * 64;
  if (nb < 2) {
    const int head = nb * 2 + nh;            // this wave owns one full head
    const int col0 = nb * 128 + nh * 64;
    float al[4], ar[4];
    #pragma unroll
    for (int nt = 0; nt < 4; nt++) {
      al[nt] = attn_l[head * 64 + nt * 16 + cn];
      ar[nt] = attn_r[head * 64 + nt * 16 + cn];
    }
    #pragma unroll
    for (int mt = 0; mt < 4; mt++)
      #pragma unroll
      for (int r = 0; r < 4; r++) {
        const int row = r0 + mt * 16 + q * 4 + r;
        float pl = 0.f, pr = 0.f;
        #pragma unroll
        for (int nt = 0; nt < 4; nt++) {
          pl = fmaf(acc[mt][nt][r], al[nt], pl);
          pr = fmaf(acc[mt][nt][r], ar[nt], pr);
        }
        #pragma unroll
        for (int o = 1; o < 16; o <<= 1) {   // reduce over the 16 cn lanes
          pl += __shfl_xor(pl, o, 64);
          pr += __shfl_xor(pr, o, 64);
        }
        if (row < N_NODES) {
          #pragma unroll
          for (int nt = 0; nt < 4; nt++)
            hbuf[(size_t)row * 256 + col0 + nt * 16 + cn] = f2bf(acc[mt][nt][r]);
          if (cn == 0) {
            el[row * 4 + head] = pl;
            er[row * 4 + head] = pr;
          }
        }
      }
  } else {
    const int rc0 = (nb - 2) * 128 + nh * 64;
    #pragma unroll
    for (int mt = 0; mt < 4; mt++)
      #pragma unroll
      for (int r = 0; r < 4; r++) {
        const int row = r0 + mt * 16 + q * 4 + r;
        if (row < N_NODES)
          #pragma unroll
          for (int nt = 0; nt < 4; nt++) {
            float v = acc[mt][nt][r] + bias[rc0 + nt * 16 + cn];
            resbuf[(size_t)row * 256 + rc0 + nt * 16 + cn] = f2bf(v);
          }
      }
  }
}

// ---------------- CSR build ----------------
__global__ __launch_bounds__(256) void k_scan1(const int* __restrict__ deg,
                                               int* __restrict__ rs, int* __restrict__ bsums)
{
  __shared__ int tmp[256];
  const int t = threadIdx.x;
  const int base = blockIdx.x * 1024 + t * 4;
  int v0 = 0, v1 = 0, v2 = 0, v3 = 0;
  if (base + 0 < N_NODES) v0 = deg[base + 0];
  if (base + 1 < N_NODES) v1 = deg[base + 1];
  if (base + 2 < N_NODES) v2 = deg[base + 2];
  if (base + 3 < N_NODES) v3 = deg[base + 3];
  const int tsum = v0 + v1 + v2 + v3;
  tmp[t] = tsum;
  __syncthreads();
  for (int o = 1; o < 256; o <<= 1) {
    int x = (t >= o) ? tmp[t - o] : 0;
    __syncthreads();
    tmp[t] += x;
    __syncthreads();
  }
  const int excl = tmp[t] - tsum;
  if (base + 0 < N_NODES) rs[base + 0] = excl;
  if (base + 1 < N_NODES) rs[base + 1] = excl + v0;
  if (base + 2 < N_NODES) rs[base + 2] = excl + v0 + v1;
  if (base + 3 < N_NODES) rs[base + 3] = excl + v0 + v1 + v2;
  if (t == 255) bsums[blockIdx.x] = tmp[t];
}

// scan of block sums folded in (each block redundantly scans 98 values)
__global__ __launch_bounds__(256) void k_scan3(int* __restrict__ rs,
                                               const int* __restrict__ bsums,
                                               int* __restrict__ cursor)
{
  __shared__ int sb[128];
  const int t = threadIdx.x;
  int raw = 0;
  if (t < 128) { raw = (t < 98) ? bsums[t] : 0; sb[t] = raw; }
  __syncthreads();
  for (int o = 1; o < 128; o <<= 1) {
    int x = (t >= o && t < 128) ? sb[t - o] : 0;
    __syncthreads();
    if (t < 128) sb[t] += x;
    __syncthreads();
  }
  if (t < 128) sb[t] -= raw;   // exclusive
  __syncthreads();
  const int i = blockIdx.x * 256 + t;
  if (i < N_NODES) {
    int v = rs[i] + sb[i >> 10];
    rs[i] = v;
    cursor[i] = v;
  } else if (i == N_NODES) {
    rs[N_NODES] = N_EDGES;
  }
}

__global__ __launch_bounds__(256) void k_scatter(const int* __restrict__ src,
                                                 const int* __restrict__ dst,
                                                 int* __restrict__ cursor,
                                                 int* __restrict__ esrc)
{
  int e = blockIdx.x * 256 + threadIdx.x;
  if (e >= N_EDGES) return;
  int d = dst[e];
  int pos = atomicAdd(&cursor[d], 1);
  esrc[pos] = src[e];
}

// ---------------- fused softmax + aggregation + residual/ELU/head-mean ------
// one wave per dst node; 8-deep edge batching for memory-level parallelism
__global__ __launch_bounds__(256) void k_agg(
    const unsigned short* __restrict__ hbuf, const unsigned short* __restrict__ resbuf,
    const float* __restrict__ el, const float* __restrict__ er,
    const int* __restrict__ rs, const int* __restrict__ esrc,
    float* __restrict__ out, float* __restrict__ bn)
{
  const int lane = threadIdx.x & 63;
  const int head = lane >> 4;
  const int waveG = blockIdx.x * 4 + (threadIdx.x >> 6);
  const int nW = gridDim.x * 4;
  float4 s4 = make_float4(0.f, 0.f, 0.f, 0.f);
  float4 q4 = make_float4(0.f, 0.f, 0.f, 0.f);
  for (int n = waveG; n < N_NODES; n += nW) {
    const int nu = __builtin_amdgcn_readfirstlane(n);
    const int p0 = __builtin_amdgcn_readfirstlane(rs[nu]);
    const int p1 = __builtin_amdgcn_readfirstlane(rs[nu + 1]);
    const float ern = er[nu * 4 + head];
    float4 acc = make_float4(0.f, 0.f, 0.f, 0.f);
    float ssum = 0.f;
    int p = p0;
    for (; p + 8 <= p1; p += 8) {            // 8 edges in flight
      int sn[8];
      #pragma unroll
      for (int i = 0; i < 8; i++) sn[i] = esrc[p + i];
      float ev[8];
      #pragma unroll
      for (int i = 0; i < 8; i++) ev[i] = el[sn[i] * 4 + head];
      ushort4 hv[8];
      #pragma unroll
      for (int i = 0; i < 8; i++)
        hv[i] = *(const ushort4*)(hbuf + (size_t)sn[i] * 256 + lane * 4);
      #pragma unroll
      for (int i = 0; i < 8; i++) {
        float e = ev[i] + ern;
        e = (e > 0.f) ? e : NEG_SLOPE * e;
        const float wgt = __expf(e);
        ssum += wgt;
        acc.x = fmaf(wgt, bf2f(hv[i].x), acc.x);
        acc.y = fmaf(wgt, bf2f(hv[i].y), acc.y);
        acc.z = fmaf(wgt, bf2f(hv[i].z), acc.z);
        acc.w = fmaf(wgt, bf2f(hv[i].w), acc.w);
      }
    }
    for (; p + 4 <= p1; p += 4) {            // 4-wide step
      int sn[4];
      #pragma unroll
      for (int i = 0; i < 4; i++) sn[i] = esrc[p + i];
      float ev[4];
      #pragma unroll
      for (int i = 0; i < 4; i++) ev[i] = el[sn[i] * 4 + head];
      ushort4 hv[4];
      #pragma unroll
      for (int i = 0; i < 4; i++)
        hv[i] = *(const ushort4*)(hbuf + (size_t)sn[i] * 256 + lane * 4);
      #pragma unroll
      for (int i = 0; i < 4; i++) {
        float e = ev[i] + ern;
        e = (e > 0.f) ? e : NEG_SLOPE * e;
        const float wgt = __expf(e);
        ssum += wgt;
        acc.x = fmaf(wgt, bf2f(hv[i].x), acc.x);
        acc.y = fmaf(wgt, bf2f(hv[i].y), acc.y);
        acc.z = fmaf(wgt, bf2f(hv[i].z), acc.z);
        acc.w = fmaf(wgt, bf2f(hv[i].w), acc.w);
      }
    }
    for (; p < p1; p++) {                    // tail
      int sn = esrc[p];
      float e = el[sn * 4 + head] + ern;
      e = (e > 0.f) ? e : NEG_SLOPE * e;
      const float wgt = __expf(e);
      ssum += wgt;
      const ushort4 hv4 = *(const ushort4*)(hbuf + (size_t)sn * 256 + lane * 4);
      acc.x = fmaf(wgt, bf2f(hv4.x), acc.x);
      acc.y = fmaf(wgt, bf2f(hv4.y), acc.y);
      acc.z = fmaf(wgt, bf2f(hv4.z), acc.z);
      acc.w = fmaf(wgt, bf2f(hv4.w), acc.w);
    }
    const float inv = (p1 > p0) ? (1.0f / ssum) : 0.f;
    const ushort4 rv4 = *(const ushort4*)(resbuf + (size_t)nu * 256 + lane * 4);
    float4 v;
    v.x = fmaf(acc.x, inv, bf2f(rv4.x));
    v.y = fmaf(acc.y, inv, bf2f(rv4.y));
    v.z = fmaf(acc.z, inv, bf2f(rv4.z));
    v.w = fmaf(acc.w, inv, bf2f(rv4.w));
    v.x = (v.x > 0.f) ? v.x : (__expf(v.x) - 1.f);
    v.y = (v.y > 0.f) ? v.y : (__expf(v.y) - 1.f);
    v.z = (v.z > 0.f) ? v.z : (__expf(v.z) - 1.f);
    v.w = (v.w > 0.f) ? v.w : (__expf(v.w) - 1.f);
    v.x += __shfl_xor(v.x, 16, 64);  v.x += __shfl_xor(v.x, 32, 64);
    v.y += __shfl_xor(v.y, 16, 64);  v.y += __shfl_xor(v.y, 32, 64);
    v.z += __shfl_xor(v.z, 16, 64);  v.z += __shfl_xor(v.z, 32, 64);
    v.w += __shfl_xor(v.w, 16, 64);  v.w += __shfl_xor(v.w, 32, 64);
    if (lane < 16) {
      v.x *= 0.25f; v.y *= 0.25f; v.z *= 0.25f; v.w *= 0.25f;
      *(float4*)(out + (size_t)nu * 64 + lane * 4) = v;
      s4.x += v.x; s4.y += v.y; s4.z += v.z; s4.w += v.w;
      q4.x += v.x * v.x; q4.y += v.y * v.y; q4.z += v.z * v.z; q4.w += v.w * v.w;
    }
  }
  __shared__ float lsum[64], lsq[64];
  if (threadIdx.x < 64) { lsum[threadIdx.x] = 0.f; lsq[threadIdx.x] = 0.f; }
  __syncthreads();
  if (lane < 16) {
    atomicAdd(&lsum[lane * 4 + 0], s4.x);  atomicAdd(&lsq[lane * 4 + 0], q4.x);
    atomicAdd(&lsum[lane * 4 + 1], s4.y);  atomicAdd(&lsq[lane * 4 + 1], q4.y);
    atomicAdd(&lsum[lane * 4 + 2], s4.z);  atomicAdd(&lsq[lane * 4 + 2], q4.z);
    atomicAdd(&lsum[lane * 4 + 3], s4.w);  atomicAdd(&lsq[lane * 4 + 3], q4.w);
  }
  __syncthreads();
  if (threadIdx.x < 64) {
    atomicAdd(&bn[threadIdx.x], lsum[threadIdx.x]);
    atomicAdd(&bn[64 + threadIdx.x], lsq[threadIdx.x]);
  }
}

// ---------------- batchnorm (stats folded in) ----------------
__global__ __launch_bounds__(256) void k_bn_apply(float* __restrict__ out,
                                                  const float* __restrict__ bn,
                                                  const float* __restrict__ gamma,
                                                  const float* __restrict__ beta)
{
  __shared__ float sc[64], sh[64];
  const int t = threadIdx.x;
  if (t < 64) {
    float mean = bn[t] * (1.0f / N_NODES);
    float var = bn[64 + t] * (1.0f / N_NODES) - mean * mean;
    float s = gamma[t] * rsqrtf(var + BN_EPS);
    sc[t] = s;
    sh[t] = beta[t] - mean * s;
  }
  __syncthreads();
  const int i = blockIdx.x * 256 + t;
  if (i >= N_NODES * 16) return;
  const int d0 = (i & 15) * 4;
  float4 v = *(float4*)(out + (size_t)i * 4);
  v.x = fmaf(v.x, sc[d0 + 0], sh[d0 + 0]);
  v.y = fmaf(v.y, sc[d0 + 1], sh[d0 + 1]);
  v.z = fmaf(v.z, sc[d0 + 2], sh[d0 + 2]);
  v.w = fmaf(v.w, sc[d0 + 3], sh[d0 + 3]);
  *(float4*)(out + (size_t)i * 4) = v;
}

extern "C" void kernel_launch(void* const* d_in, const int* in_sizes, int n_in,
                              void* d_out, int out_size, void* d_ws, size_t ws_size,
                              hipStream_t stream)
{
  const float* feats  = (const float*)d_in[0];
  const int*   src    = (const int*)d_in[1];
  const int*   dst    = (const int*)d_in[2];
  const float* fc_w   = (const float*)d_in[3];
  const float* attn_l = (const float*)d_in[4];
  const float* attn_r = (const float*)d_in[5];
  const float* res_w  = (const float*)d_in[6];
  const float* bias   = (const float*)d_in[7];
  const float* gamma  = (const float*)d_in[8];
  const float* beta   = (const float*)d_in[9];

  char* ws = (char*)d_ws;
  unsigned short* Ab     = (unsigned short*)(ws + OFF_AB);
  unsigned short* Bb     = (unsigned short*)(ws + OFF_BB);
  unsigned short* hbuf   = (unsigned short*)(ws + OFF_H);
  unsigned short* resbuf = (unsigned short*)(ws + OFF_RES);
  float* elb    = (float*)(ws + OFF_EL);
  float* erb    = (float*)(ws + OFF_ER);
  int*   deg    = (int*)(ws + OFF_DEG);
  int*   rsb    = (int*)(ws + OFF_RS);
  int*   curb   = (int*)(ws + OFF_CUR);
  int*   esrc   = (int*)(ws + OFF_ESRC);
  int*   bsums  = (int*)(ws + OFF_BS);
  float* bnb    = (float*)(ws + OFF_BN);
  float* outp   = (float*)d_out;

  hipMemsetAsync(deg, 0, N_NODES * sizeof(int), stream);
  hipMemsetAsync(bnb, 0, 128 * sizeof(float), stream);

  k_pre<<<12538, 256, 0, stream>>>(feats, fc_w, res_w, dst, Ab, Bb, deg);
  k_mm<<<dim3(782, 4), 256, 0, stream>>>(Ab, Bb, bias, attn_l, attn_r,
                                         hbuf, resbuf, elb, erb);
  k_scan1<<<98, 256, 0, stream>>>(deg, rsb, bsums);
  k_scan3<<<391, 256, 0, stream>>>(rsb, bsums, curb);
  k_scatter<<<6250, 256, 0, stream>>>(src, dst, curb, esrc);
  k_agg<<<2048, 256, 0, stream>>>(hbuf, resbuf, elb, erb, rsb, esrc, outp, bnb);
  k_bn_apply<<<6250, 256, 0, stream>>>(outp, bnb, gamma, beta);
}